// Round 9
// baseline (144.139 us; speedup 1.0000x reference)
//
#include <hip/hip_runtime.h>

// BCH truncated series on 3D periodic velocity fields — v7: barrier-free gather.
// out_i = L_i + R_i + 0.25 * sum_j [ dL_i^j * R_j - dR_i^j * L_j ]
// (central differences, circulant bounds, channels-first (B,D,X,Y,Z)).
//
// v7 theory (from v0/v3/v4 fill-rate data: time ~ cache-side traffic / fill,
// fill ~ duty cycle of outstanding loads): v4's LDS+barrier two-phase halves
// duty (fill 11.2 B/cy/CU vs barrier-free v0's 15.8). Drop LDS + barrier;
// y+-1 gathered from global like x+-1 — those rows are the block's own
// center plane (24 KB, L1-resident), so y-gathers are L1 hits that cost
// issue slots but no slow-queue occupancy. Slow traffic stays at v4's
// 314 MB; 30 independent f4 loads ride ONE latency window; waves never
// drain. Occupancy now VGPR-limited only.
// Prediction: dur 45.4 -> 32-38 us, occupancy 33 -> 45-65%, LDS 0.
// Falsifier: dur ~45 at high occupancy => hard per-CU vmem cap => next
// lever is traffic (2-plane blocks).
//
// Kept: XCD swizzle (v6: FETCH 62->52 MB), NT stores (v5: neutral/harmless),
// z via width-32 shuffles, grid 4096, no __launch_bounds__ min-waves pin
// (R2: spill disaster).

namespace {
constexpr int Xd = 128, Yd = 128, Zd = 128, Dd = 3;
constexpr int Sd  = Xd * Yd * Zd;   // channel stride
constexpr int YZd = Yd * Zd;        // x-plane stride
constexpr int YT  = 8;              // y rows per block
constexpr int NXCD = 8;

typedef float f32x4_t __attribute__((ext_vector_type(4)));

__device__ inline float4 f4sub(float4 a, float4 b) {
    return make_float4(a.x - b.x, a.y - b.y, a.z - b.z, a.w - b.w);
}
__device__ inline float4 f4add(float4 a, float4 b) {
    return make_float4(a.x + b.x, a.y + b.y, a.z + b.z, a.w + b.w);
}
__device__ inline float4 f4mul(float4 a, float4 b) {
    return make_float4(a.x * b.x, a.y * b.y, a.z * b.z, a.w * b.w);
}
__device__ inline float4 f4fma(float4 a, float4 b, float4 c) {
    return make_float4(fmaf(a.x, b.x, c.x), fmaf(a.y, b.y, c.y),
                       fmaf(a.z, b.z, c.z), fmaf(a.w, b.w, c.w));
}
// c - a*b
__device__ inline float4 f4fms(float4 a, float4 b, float4 c) {
    return make_float4(fmaf(-a.x, b.x, c.x), fmaf(-a.y, b.y, c.y),
                       fmaf(-a.z, b.z, c.z), fmaf(-a.w, b.w, c.w));
}
__device__ inline void store_nt(float* p, float4 v) {
    __builtin_nontemporal_store(*(const f32x4_t*)&v, (f32x4_t*)p);
}
} // namespace

__global__ void __launch_bounds__(256)
bch_gather(const float* __restrict__ L, const float* __restrict__ R,
           float* __restrict__ O)
{
    const int t  = threadIdx.x;
    const int zc = t & 31;          // z chunk (float4) within line
    const int ly = t >> 5;          // local y row 0..7

    // XCD-aware swizzle: grid 4096 = 8 XCDs x 512-block contiguous chunks.
    const int bid = blockIdx.x;
    int bb = (bid & (NXCD - 1)) * (4096 / NXCD) + (bid >> 3);

    const int yt = bb & 15; bb >>= 4;    // y tile (innermost on each XCD)
    const int x  = bb & 127; bb >>= 7;
    const int b  = bb;

    const int y  = yt * YT + ly;
    const int z0 = zc * 4;

    const int fbase = b * (Dd * Sd) + x * YZd + y * Zd + z0;
    const float* pL = L + fbase;
    const float* pR = R + fbase;
    float*       pO = O + fbase;

    const int oxp = (((x + 1) & 127) - x) * YZd;  // wrapped x+1 plane offset
    const int oxm = (((x - 1) & 127) - x) * YZd;  // wrapped x-1 plane offset
    const int oym = (((y - 1) & 127) - y) * Zd;   // wrapped y-1 row offset
    const int oyp = (((y + 1) & 127) - y) * Zd;   // wrapped y+1 row offset
    const int zlm = (zc + 31) & 31;   // shfl source lane for z-1 (.w)
    const int zlp = (zc + 1) & 31;    // shfl source lane for z+4 (.x)

    // ---- issue ALL 30 float4 loads up front (one latency window) ----
    float4 BL[3], BR[3];                     // center
    float4 XPL[3], XML[3], XPR[3], XMR[3];   // x+1 / x-1 (L2)
    float4 YPL[3], YML[3], YPR[3], YMR[3];   // y+1 / y-1 (L1: own plane)
#pragma unroll
    for (int d = 0; d < 3; ++d) {
        BL[d]  = *(const float4*)(pL + d * Sd);
        BR[d]  = *(const float4*)(pR + d * Sd);
        XPL[d] = *(const float4*)(pL + oxp + d * Sd);
        XML[d] = *(const float4*)(pL + oxm + d * Sd);
        XPR[d] = *(const float4*)(pR + oxp + d * Sd);
        XMR[d] = *(const float4*)(pR + oxm + d * Sd);
        YPL[d] = *(const float4*)(pL + oyp + d * Sd);
        YML[d] = *(const float4*)(pL + oym + d * Sd);
        YPR[d] = *(const float4*)(pR + oyp + d * Sd);
        YMR[d] = *(const float4*)(pR + oym + d * Sd);
    }

#pragma unroll
    for (int i = 0; i < 3; ++i) {
        // j = 0 (x): gathered planes
        float4 dl = f4sub(XPL[i], XML[i]);
        float4 dr = f4sub(XPR[i], XMR[i]);
        float4 br = f4fms(dr, BL[0], f4mul(dl, BR[0]));

        // j = 1 (y): gathered rows (L1-resident)
        dl = f4sub(YPL[i], YML[i]);
        dr = f4sub(YPR[i], YMR[i]);
        br = f4fms(dr, BL[1], f4fma(dl, BR[1], br));

        // j = 2 (z): shift-in-register + width-32 shuffles (wrap in line)
        const float lzm = __shfl(BL[i].w, zlm, 32);
        const float lzp = __shfl(BL[i].x, zlp, 32);
        const float rzm = __shfl(BR[i].w, zlm, 32);
        const float rzp = __shfl(BR[i].x, zlp, 32);
        dl = make_float4(BL[i].y - lzm, BL[i].z - BL[i].x,
                         BL[i].w - BL[i].y, lzp - BL[i].z);
        dr = make_float4(BR[i].y - rzm, BR[i].z - BR[i].x,
                         BR[i].w - BR[i].y, rzp - BR[i].z);
        br = f4fms(dr, BL[2], f4fma(dl, BR[2], br));

        float4 out = f4add(BL[i], BR[i]);
        const float4 q = make_float4(0.25f, 0.25f, 0.25f, 0.25f);
        out = f4fma(q, br, out);
        store_nt(pO + i * Sd, out);
    }
}

extern "C" void kernel_launch(void* const* d_in, const int* in_sizes, int n_in,
                              void* d_out, int out_size, void* d_ws, size_t ws_size,
                              hipStream_t stream)
{
    const float* L = (const float*)d_in[0];
    const float* R = (const float*)d_in[1];
    float*       O = (float*)d_out;

    const int nblocks = (Yd / YT) * Xd * 2;   // 4096
    bch_gather<<<dim3(nblocks), dim3(256), 0, stream>>>(L, R, O);
}

// Round 10
// 144.049 us; speedup vs baseline: 1.0006x; 1.0006x over previous
//
#include <hip/hip_runtime.h>

// BCH truncated series on 3D periodic velocity fields — v8: 2-plane blocks.
// out_i = L_i + R_i + 0.25 * sum_j [ dL_i^j * R_j - dR_i^j * L_j ]
// (central differences, circulant bounds, channels-first (B,D,X,Y,Z)).
//
// v8 theory: all 6 prior variants pin at ~2.2-2.6 TB/s effective HBM /
// ~7-8 TB/s cache-side fill regardless of structure (LDS/no-LDS, barrier/
// no-barrier, occupancy 17-43%) => per-CU outstanding-miss (MSHR) x latency
// cap. Only lever: L1-missing bytes per output point. v7 = 72 B/pt (center
// 24 + x-gathers 48). v8 outputs TWO adjacent x-planes per block: 4 center
// planes (x-1..x+2) per 2 outputs = 48 B/pt (0.67x). Phase B reuses phase
// A's registers (x-1 regs <- x+2, y regs <- x+1 rows), so peak liveness
// stays ~v7 + 12 carried f4.
// Prediction: dur 47.2 -> 33-39 us, FETCH 45-55 MB, WRITE ~49 MB (rise =
// spill = revert), VGPR 100-140. Falsifier: dur >= ~43 us without spill =>
// fixed per-point cost binds => practical roofline.
//
// Kept: barrier-free gather (v7), XCD swizzle (v6), NT stores (v5),
// z via width-32 shuffles, no __launch_bounds__ min-waves pin (R2).

namespace {
constexpr int Xd = 128, Yd = 128, Zd = 128, Dd = 3;
constexpr int Sd  = Xd * Yd * Zd;   // channel stride
constexpr int YZd = Yd * Zd;        // x-plane stride
constexpr int YT  = 8;              // y rows per block
constexpr int NXCD = 8;
constexpr int NBLK = (Yd / YT) * (Xd / 2) * 2;   // 2048

typedef float f32x4_t __attribute__((ext_vector_type(4)));

__device__ inline float4 f4sub(float4 a, float4 b) {
    return make_float4(a.x - b.x, a.y - b.y, a.z - b.z, a.w - b.w);
}
__device__ inline float4 f4add(float4 a, float4 b) {
    return make_float4(a.x + b.x, a.y + b.y, a.z + b.z, a.w + b.w);
}
__device__ inline float4 f4mul(float4 a, float4 b) {
    return make_float4(a.x * b.x, a.y * b.y, a.z * b.z, a.w * b.w);
}
__device__ inline float4 f4fma(float4 a, float4 b, float4 c) {
    return make_float4(fmaf(a.x, b.x, c.x), fmaf(a.y, b.y, c.y),
                       fmaf(a.z, b.z, c.z), fmaf(a.w, b.w, c.w));
}
// c - a*b
__device__ inline float4 f4fms(float4 a, float4 b, float4 c) {
    return make_float4(fmaf(-a.x, b.x, c.x), fmaf(-a.y, b.y, c.y),
                       fmaf(-a.z, b.z, c.z), fmaf(-a.w, b.w, c.w));
}
__device__ inline void store_nt(float* p, float4 v) {
    __builtin_nontemporal_store(*(const f32x4_t*)&v, (f32x4_t*)p);
}
} // namespace

__global__ void __launch_bounds__(256)
bch_pair(const float* __restrict__ L, const float* __restrict__ R,
         float* __restrict__ O)
{
    const int t  = threadIdx.x;
    const int zc = t & 31;          // z chunk (float4) within line
    const int ly = t >> 5;          // local y row 0..7

    // XCD-aware swizzle: grid 2048 = 8 XCDs x 256-block contiguous chunks.
    const int bid = blockIdx.x;
    int bb = (bid & (NXCD - 1)) * (NBLK / NXCD) + (bid >> 3);

    const int yt = bb & 15; bb >>= 4;    // y tile (innermost on each XCD)
    const int xp = bb & 63; bb >>= 6;    // x-pair index
    const int b  = bb;

    const int x0 = xp * 2;               // output planes x0, x0+1
    const int y  = yt * YT + ly;
    const int z0 = zc * 4;

    const int fbase = b * (Dd * Sd) + x0 * YZd + y * Zd + z0;
    const float* pL = L + fbase;
    const float* pR = R + fbase;
    float*       pO = O + fbase;

    const int oxm = (((x0 - 1) & 127) - x0) * YZd;  // wrapped x0-1 plane
    const int ox2 = (((x0 + 2) & 127) - x0) * YZd;  // wrapped x0+2 plane
    const int oym = (((y - 1) & 127) - y) * Zd;     // wrapped y-1 row
    const int oyp = (((y + 1) & 127) - y) * Zd;     // wrapped y+1 row
    const int zlm = (zc + 31) & 31;   // shfl source lane for z-1 (.w)
    const int zlp = (zc + 1) & 31;    // shfl source lane for z+4 (.x)

    // Shared per-plane compute+store (identical op order to v7 per point).
    auto compute_store = [&](const float4 (&CL)[3],  const float4 (&CR)[3],
                             const float4 (&XPL)[3], const float4 (&XPR)[3],
                             const float4 (&XML)[3], const float4 (&XMR)[3],
                             const float4 (&YPL)[3], const float4 (&YPR)[3],
                             const float4 (&YML)[3], const float4 (&YMR)[3],
                             int ooff) {
#pragma unroll
        for (int i = 0; i < 3; ++i) {
            // j = 0 (x)
            float4 dl = f4sub(XPL[i], XML[i]);
            float4 dr = f4sub(XPR[i], XMR[i]);
            float4 br = f4fms(dr, CL[0], f4mul(dl, CR[0]));

            // j = 1 (y)
            dl = f4sub(YPL[i], YML[i]);
            dr = f4sub(YPR[i], YMR[i]);
            br = f4fms(dr, CL[1], f4fma(dl, CR[1], br));

            // j = 2 (z): shift-in-register + width-32 shuffles
            const float lzm = __shfl(CL[i].w, zlm, 32);
            const float lzp = __shfl(CL[i].x, zlp, 32);
            const float rzm = __shfl(CR[i].w, zlm, 32);
            const float rzp = __shfl(CR[i].x, zlp, 32);
            dl = make_float4(CL[i].y - lzm, CL[i].z - CL[i].x,
                             CL[i].w - CL[i].y, lzp - CL[i].z);
            dr = make_float4(CR[i].y - rzm, CR[i].z - CR[i].x,
                             CR[i].w - CR[i].y, rzp - CR[i].z);
            br = f4fms(dr, CL[2], f4fma(dl, CR[2], br));

            float4 out = f4add(CL[i], CR[i]);
            const float4 q = make_float4(0.25f, 0.25f, 0.25f, 0.25f);
            out = f4fma(q, br, out);
            store_nt(pO + ooff + i * Sd, out);
        }
    };

    // ---- Phase A: plane x0 ----
    float4 XmL[3], XmR[3];      // x0-1 (phase B reuses these for x0+2)
    float4 C0L[3], C0R[3];      // x0 center (carried to phase B)
    float4 C1L[3], C1R[3];      // x0+1 center (carried; phase B's center)
    float4 YpL[3], YmL[3], YpR[3], YmR[3];   // y gathers (reused in B)
#pragma unroll
    for (int d = 0; d < 3; ++d) {
        XmL[d] = *(const float4*)(pL + oxm + d * Sd);
        XmR[d] = *(const float4*)(pR + oxm + d * Sd);
        C0L[d] = *(const float4*)(pL + d * Sd);
        C0R[d] = *(const float4*)(pR + d * Sd);
        C1L[d] = *(const float4*)(pL + YZd + d * Sd);
        C1R[d] = *(const float4*)(pR + YZd + d * Sd);
        YpL[d] = *(const float4*)(pL + oyp + d * Sd);
        YmL[d] = *(const float4*)(pL + oym + d * Sd);
        YpR[d] = *(const float4*)(pR + oyp + d * Sd);
        YmR[d] = *(const float4*)(pR + oym + d * Sd);
    }
    // out(x0): center C0, dx = C1 - Xm, dy from Y at x0, dz from C0.
    compute_store(C0L, C0R, C1L, C1R, XmL, XmR, YpL, YpR, YmL, YmR, 0);

    // ---- Phase B: plane x0+1 (reuse Xm <- x0+2, Y <- rows at x0+1) ----
#pragma unroll
    for (int d = 0; d < 3; ++d) {
        XmL[d] = *(const float4*)(pL + ox2 + d * Sd);
        XmR[d] = *(const float4*)(pR + ox2 + d * Sd);
        YpL[d] = *(const float4*)(pL + YZd + oyp + d * Sd);
        YmL[d] = *(const float4*)(pL + YZd + oym + d * Sd);
        YpR[d] = *(const float4*)(pR + YZd + oyp + d * Sd);
        YmR[d] = *(const float4*)(pR + YZd + oym + d * Sd);
    }
    // out(x0+1): center C1, dx = (x0+2) - C0, dy from Y at x0+1, dz from C1.
    compute_store(C1L, C1R, XmL, XmR, C0L, C0R, YpL, YpR, YmL, YmR, YZd);
}

extern "C" void kernel_launch(void* const* d_in, const int* in_sizes, int n_in,
                              void* d_out, int out_size, void* d_ws, size_t ws_size,
                              hipStream_t stream)
{
    const float* L = (const float*)d_in[0];
    const float* R = (const float*)d_in[1];
    float*       O = (float*)d_out;

    bch_pair<<<dim3(NBLK), dim3(256), 0, stream>>>(L, R, O);
}

// Round 11
// 137.797 us; speedup vs baseline: 1.0460x; 1.0454x over previous
//
#include <hip/hip_runtime.h>

// BCH truncated series on 3D periodic velocity fields — v9 = revert to v5,
// the session-best measured kernel (top-5 dispatch mean 44.65 us).
// out_i = L_i + R_i + 0.25 * sum_j [ dL_i^j * R_j - dR_i^j * L_j ]
// (central differences, circulant bounds, channels-first (B,D,X,Y,Z)).
//
// Session ledger (per-dispatch):
//   v0 gather 57.0 | v1 march8 50.6 | v2 (256,4)-pin SPILL 103 | v3 march4 52.8
//   v4 plane+LDS 45.5 | v5 +NT 44.7 | v6 +XCDswz 45.4 (FETCH 62->52, time flat)
//   v7 no-barrier 47.2 | v8 2-plane 47.9 (traffic lever null)
// Conclusion: time pinned ~45-48 us across 5 structures; insensitive to
// traffic (±60%), occupancy (17-43%), barriers, MLP (6-48 f4/thread), HBM
// fetch (52-80 MB). All visible counters <40% busy => binding resource not
// in SQ/TCC top-level set (likely L2-miss/fabric service). v5 is the best
// point on the plateau; restoring it as the final artifact.
//
// Structure: one x-plane per block; x+-1 planes gathered (12 independent f4
// loads) issued up front with center loads (one latency window); y+-1 from
// LDS-staged center plane (halo rows in LDS); z+-1 via width-32 shuffles;
// NT float4 output stores; grid 4096; no __launch_bounds__ min-waves pin
// (R2: (256,4) => 64-VGPR squeeze => +110 MB scratch spill, 2x slower).

namespace {
constexpr int Xd = 128, Yd = 128, Zd = 128, Dd = 3;
constexpr int Sd  = Xd * Yd * Zd;   // channel stride
constexpr int YZd = Yd * Zd;        // x-plane stride
constexpr int YT  = 8;              // y rows per block
constexpr int ZC  = 32;             // float4 chunks per z-line

typedef float f32x4_t __attribute__((ext_vector_type(4)));

__device__ inline float4 f4sub(float4 a, float4 b) {
    return make_float4(a.x - b.x, a.y - b.y, a.z - b.z, a.w - b.w);
}
__device__ inline float4 f4add(float4 a, float4 b) {
    return make_float4(a.x + b.x, a.y + b.y, a.z + b.z, a.w + b.w);
}
__device__ inline float4 f4mul(float4 a, float4 b) {
    return make_float4(a.x * b.x, a.y * b.y, a.z * b.z, a.w * b.w);
}
__device__ inline float4 f4fma(float4 a, float4 b, float4 c) {
    return make_float4(fmaf(a.x, b.x, c.x), fmaf(a.y, b.y, c.y),
                       fmaf(a.z, b.z, c.z), fmaf(a.w, b.w, c.w));
}
// c - a*b
__device__ inline float4 f4fms(float4 a, float4 b, float4 c) {
    return make_float4(fmaf(-a.x, b.x, c.x), fmaf(-a.y, b.y, c.y),
                       fmaf(-a.z, b.z, c.z), fmaf(-a.w, b.w, c.w));
}
__device__ inline void store_nt(float* p, float4 v) {
    __builtin_nontemporal_store(*(const f32x4_t*)&v, (f32x4_t*)p);
}
} // namespace

__global__ void __launch_bounds__(256)
bch_plane(const float* __restrict__ L, const float* __restrict__ R,
          float* __restrict__ O)
{
    // [0..2]=L channels, [3..5]=R channels; rows 1..YT = center, 0 / YT+1 = halo
    __shared__ float4 sP[2 * Dd][YT + 2][ZC];   // 30 KB

    const int t  = threadIdx.x;
    const int zc = t & 31;          // z chunk (float4) within line
    const int ly = t >> 5;          // local y row 0..7

    int bb = blockIdx.x;            // grid = 16 * 128 * 2 = 4096
    const int yt = bb & 15; bb >>= 4;    // y tile (low bits: 16 consecutive
    const int x  = bb & 127; bb >>= 7;   //   blocks share one x-neighborhood)
    const int b  = bb;

    const int y  = yt * YT + ly;
    const int z0 = zc * 4;

    const int fbase = b * (Dd * Sd) + x * YZd + y * Zd + z0;
    const float* pL = L + fbase;
    const float* pR = R + fbase;
    float*       pO = O + fbase;

    const int oxp = (((x + 1) & 127) - x) * YZd;  // wrapped x+1 plane offset
    const int oxm = (((x - 1) & 127) - x) * YZd;  // wrapped x-1 plane offset
    const int oym = (((y - 1) & 127) - y) * Zd;   // wrapped y-1 row offset
    const int oyp = (((y + 1) & 127) - y) * Zd;   // wrapped y+1 row offset
    const int zlm = (zc + 31) & 31;   // shfl source lane for z-1 (.w)
    const int zlp = (zc + 1) & 31;    // shfl source lane for z+4 (.x)

    // ---- issue ALL global loads up front (one latency window) ----
    float4 BL[3], BR[3];              // center plane
    float4 XPL[3], XML[3], XPR[3], XMR[3];   // x+1 / x-1 gathers
#pragma unroll
    for (int d = 0; d < 3; ++d) {
        BL[d]  = *(const float4*)(pL + d * Sd);
        BR[d]  = *(const float4*)(pR + d * Sd);
        XPL[d] = *(const float4*)(pL + oxp + d * Sd);
        XML[d] = *(const float4*)(pL + oxm + d * Sd);
        XPR[d] = *(const float4*)(pR + oxp + d * Sd);
        XMR[d] = *(const float4*)(pR + oxm + d * Sd);
    }

    const bool lo = (ly == 0);
    const bool hi = (ly == YT - 1);
    if (lo | hi) {
        const int oyh  = lo ? oym : oyp;
        const int hrow = lo ? 0 : YT + 1;
        float4 H[6];
#pragma unroll
        for (int d = 0; d < 3; ++d) {
            H[d]     = *(const float4*)(pL + oyh + d * Sd);
            H[3 + d] = *(const float4*)(pR + oyh + d * Sd);
        }
#pragma unroll
        for (int d = 0; d < 6; ++d) sP[d][hrow][zc] = H[d];
    }

    // Stage center plane in LDS.
#pragma unroll
    for (int d = 0; d < 3; ++d) {
        sP[d][ly + 1][zc]     = BL[d];
        sP[3 + d][ly + 1][zc] = BR[d];
    }
    __syncthreads();

    // y-neighbors: uniform LDS reads (halo rows included in tile).
    float4 yLm[3], yRm[3], yLp[3], yRp[3];
#pragma unroll
    for (int d = 0; d < 3; ++d) {
        yLm[d] = sP[d][ly][zc];
        yLp[d] = sP[d][ly + 2][zc];
        yRm[d] = sP[3 + d][ly][zc];
        yRp[d] = sP[3 + d][ly + 2][zc];
    }

#pragma unroll
    for (int i = 0; i < 3; ++i) {
        // j = 0 (x): from gathered planes
        float4 dl = f4sub(XPL[i], XML[i]);
        float4 dr = f4sub(XPR[i], XMR[i]);
        float4 br = f4fms(dr, BL[0], f4mul(dl, BR[0]));

        // j = 1 (y): from LDS
        dl = f4sub(yLp[i], yLm[i]);
        dr = f4sub(yRp[i], yRm[i]);
        br = f4fms(dr, BL[1], f4fma(dl, BR[1], br));

        // j = 2 (z): shift-in-register + width-32 shuffles (wrap in line)
        const float lzm = __shfl(BL[i].w, zlm, 32);
        const float lzp = __shfl(BL[i].x, zlp, 32);
        const float rzm = __shfl(BR[i].w, zlm, 32);
        const float rzp = __shfl(BR[i].x, zlp, 32);
        dl = make_float4(BL[i].y - lzm, BL[i].z - BL[i].x,
                         BL[i].w - BL[i].y, lzp - BL[i].z);
        dr = make_float4(BR[i].y - rzm, BR[i].z - BR[i].x,
                         BR[i].w - BR[i].y, rzp - BR[i].z);
        br = f4fms(dr, BL[2], f4fma(dl, BR[2], br));

        float4 out = f4add(BL[i], BR[i]);
        const float4 q = make_float4(0.25f, 0.25f, 0.25f, 0.25f);
        out = f4fma(q, br, out);
        store_nt(pO + i * Sd, out);
    }
}

extern "C" void kernel_launch(void* const* d_in, const int* in_sizes, int n_in,
                              void* d_out, int out_size, void* d_ws, size_t ws_size,
                              hipStream_t stream)
{
    const float* L = (const float*)d_in[0];
    const float* R = (const float*)d_in[1];
    float*       O = (float*)d_out;

    const int nblocks = (Yd / YT) * Xd * 2;   // 4096
    bch_plane<<<dim3(nblocks), dim3(256), 0, stream>>>(L, R, O);
}